// Round 1
// baseline (375.183 us; speedup 1.0000x reference)
//
#include <hip/hip_runtime.h>
#include <hip/hip_bf16.h>

// B=4, H=W=64 -> N=4096, C=256, d=32
// ws layout (bytes):
//   qk    [B*N][64] bf16            @ 0        (2 MB)   cols 0..31 q, 32..63 k
//   vT    [B][C][N] bf16            @ 2 MB     (8 MB)   v transposed, later scaled by 1/Z
//   wallT [320][256] bf16           @ 10 MB    (160 KB) packed W^T (q|k|v)
//   ball  [320] f32                 @ +163840  (1.25 KB)
//   zpart [4][B*N] f32              @ +1280    (256 KB)
//   rz    [B*N] f32                 @ +262144  (64 KB)

typedef __attribute__((ext_vector_type(4))) float  f32x4;
typedef __attribute__((ext_vector_type(8))) short  bf8;
typedef __attribute__((ext_vector_type(4))) short  bf4;

__device__ __forceinline__ short f2bf(float f) {
    unsigned u = __builtin_bit_cast(unsigned, f);
    u += 0x7FFF + ((u >> 16) & 1);           // RNE
    return (short)(u >> 16);
}
__device__ __forceinline__ float bf2f(short h) {
    unsigned u = ((unsigned)(unsigned short)h) << 16;
    return __builtin_bit_cast(float, u);
}

// ---------------- K1: pack weights into B^T (n-major, k-contiguous) bf16 ----
__global__ __launch_bounds__(256) void pack_weights(
    const float* __restrict__ Wq, const float* __restrict__ Wk,
    const float* __restrict__ Wv, const float* __restrict__ bq,
    const float* __restrict__ bk, const float* __restrict__ bv,
    short* __restrict__ wallT, float* __restrict__ ball)
{
    int n = blockIdx.x;        // 0..319
    int k = threadIdx.x;       // 0..255
    float w;
    if (n < 32)       w = Wq[k * 32 + n];
    else if (n < 64)  w = Wk[k * 32 + (n - 32)];
    else              w = Wv[k * 256 + (n - 64)];
    wallT[n * 256 + k] = f2bf(w);
    if (k == 0) ball[n] = (n < 32) ? bq[n] : (n < 64) ? bk[n - 32] : bv[n - 64];
}

// ---------------- K2: QKV projection GEMM [16384,256] x [256,320] -----------
__global__ __launch_bounds__(256) void qkv_gemm(
    const float* __restrict__ x, const short* __restrict__ wallT,
    const float* __restrict__ ball,
    short* __restrict__ qk, short* __restrict__ vT)
{
    const int w  = threadIdx.x >> 6;
    const int l  = threadIdx.x & 63;
    const int lr = l & 15;             // A row / B col within fragment
    const int lg = l >> 4;             // k-group
    const int m0 = blockIdx.x * 64 + w * 16;

    f32x4 acc[20];
#pragma unroll
    for (int i = 0; i < 20; ++i) acc[i] = (f32x4){0.f, 0.f, 0.f, 0.f};

    const float* xrow  = x + (size_t)(m0 + lr) * 256 + lg * 8;
    const short* wbase = wallT + lr * 256 + lg * 8;

#pragma unroll
    for (int ks = 0; ks < 256; ks += 32) {
        f32x4 a0 = *(const f32x4*)(xrow + ks);
        f32x4 a1 = *(const f32x4*)(xrow + ks + 4);
        bf8 af;
#pragma unroll
        for (int t = 0; t < 4; ++t) { af[t] = f2bf(a0[t]); af[t + 4] = f2bf(a1[t]); }
#pragma unroll
        for (int nf = 0; nf < 20; ++nf) {
            bf8 bfr = *(const bf8*)(wbase + nf * 4096 + ks);
            acc[nf] = __builtin_amdgcn_mfma_f32_16x16x32_bf16(af, bfr, acc[nf], 0, 0, 0);
        }
    }

    const int b    = m0 >> 12;
    const int pix0 = (m0 & 4095) + lg * 4;
#pragma unroll
    for (int nf = 0; nf < 20; ++nf) {
        int n = nf * 16 + lr;
        float bias = ball[n];
        if (n < 64) {
#pragma unroll
            for (int r = 0; r < 4; ++r) {
                int m = m0 + lg * 4 + r;
                qk[(size_t)m * 64 + n] = f2bf(acc[nf][r] + bias);
            }
        } else {
            bf4 pv;
#pragma unroll
            for (int r = 0; r < 4; ++r) pv[r] = f2bf(acc[nf][r] + bias);
            *(bf4*)(vT + (size_t)b * 1048576 + (size_t)(n - 64) * 4096 + pix0) = pv;
        }
    }
}

// ---------------- K3: pass A — Z_i = sum_j exp(q_i . k_j)  (max-free) -------
__global__ __launch_bounds__(256) void zsum_kernel(
    const short* __restrict__ qk, float* __restrict__ zpart)
{
    const int w  = threadIdx.x >> 6, l = threadIdx.x & 63;
    const int lr = l & 15, lg = l >> 4;
    const int b  = blockIdx.z, jc = blockIdx.y;
    const int i0 = blockIdx.x * 64 + w * 16;

    bf8 aq = *(const bf8*)(qk + (size_t)(b * 4096 + i0 + lr) * 64 + lg * 8);
    float zacc[4] = {0.f, 0.f, 0.f, 0.f};

    const short* kbase = qk + (size_t)(b * 4096 + jc * 1024) * 64 + 32 + lg * 8;
    for (int j = 0; j < 1024; j += 32) {
        bf8 b0 = *(const bf8*)(kbase + (size_t)(j + lr) * 64);
        bf8 b1 = *(const bf8*)(kbase + (size_t)(j + 16 + lr) * 64);
        f32x4 z4 = (f32x4){0.f, 0.f, 0.f, 0.f};
        f32x4 e0 = __builtin_amdgcn_mfma_f32_16x16x32_bf16(aq, b0, z4, 0, 0, 0);
        f32x4 e1 = __builtin_amdgcn_mfma_f32_16x16x32_bf16(aq, b1, z4, 0, 0, 0);
#pragma unroll
        for (int r = 0; r < 4; ++r) {
            zacc[r] += __expf(fminf(e0[r], 80.f));
            zacc[r] += __expf(fminf(e1[r], 80.f));
        }
    }
#pragma unroll
    for (int r = 0; r < 4; ++r) {
        float z = zacc[r];
        for (int msk = 1; msk < 16; msk <<= 1) z += __shfl_xor(z, msk);
        if (lr == 0) zpart[(size_t)jc * 16384 + b * 4096 + i0 + lg * 4 + r] = z;
    }
}

// ---------------- K3b: rz = 1 / sum(partials) --------------------------------
__global__ __launch_bounds__(256) void zfinish(
    const float* __restrict__ zpart, float* __restrict__ rz)
{
    int i = blockIdx.x * 256 + threadIdx.x;   // 0..16383
    float z = zpart[i] + zpart[16384 + i] + zpart[32768 + i] + zpart[49152 + i];
    rz[i] = 1.0f / z;
}

// ---------------- K4: vs = v / Z  (in place on vT, i-contiguous) ------------
__global__ __launch_bounds__(256) void vscale(
    short* __restrict__ vT, const float* __restrict__ rz)
{
    int t = blockIdx.x * 256 + threadIdx.x;
    size_t base = (size_t)t * 8;                // flat element idx into [B*C*N]
    int b = (int)(base >> 20);
    int i = (int)(base & 4095);
    bf8 v = *(bf8*)(vT + base);
    const float* rzp = rz + b * 4096 + i;
#pragma unroll
    for (int e = 0; e < 8; ++e) v[e] = f2bf(bf2f(v[e]) * rzp[e]);
    *(bf8*)(vT + base) = v;
}

// ---------------- K5: pass B — out = gamma * (P^T @ vs) + x ------------------
// block: (j-tile 64) x (C=256), 8 waves. per i-step: S^T=K.Q^T -> exp -> LDS ->
// PV mfma. QK roles: wave w -> (jf=w>>1, if=w&1). PV roles: (wj=w&3, wc=w>>2).
__global__ __launch_bounds__(512) void attn_out(
    const short* __restrict__ qk, const short* __restrict__ vT,
    const float* __restrict__ x, const float* __restrict__ gammaPtr,
    float* __restrict__ out)
{
    __shared__ __align__(16) short Plds[64][40];   // 64 j x 32 i, +8 pad
    const int w  = threadIdx.x >> 6, l = threadIdx.x & 63;
    const int lr = l & 15, lg = l >> 4;
    const int b  = blockIdx.y, jt = blockIdx.x;
    const int j0 = jt * 64;

    const int qk_jf = w >> 1;   // j strip 0..3
    const int qk_if = w & 1;    // i frag  0..1
    bf8 aK = *(const bf8*)(qk + (size_t)(b * 4096 + j0 + qk_jf * 16 + lr) * 64 + 32 + lg * 8);

    const int pv_wj = w & 3, pv_wc = w >> 2;
    f32x4 acc[8];
#pragma unroll
    for (int i = 0; i < 8; ++i) acc[i] = (f32x4){0.f, 0.f, 0.f, 0.f};

    const short* qbase = qk + (size_t)(b * 4096) * 64 + lg * 8;
    const short* vbase = vT + ((size_t)b << 20) + (size_t)(pv_wc * 128 + lr) * 4096 + lg * 8;
    const short* pvA   = &Plds[pv_wj * 16 + lr][lg * 8];

    for (int i0 = 0; i0 < 4096; i0 += 32) {
        {   // phase 1: one 16x16 S^T fragment per wave
            bf8 bQ = *(const bf8*)(qbase + (size_t)(i0 + qk_if * 16 + lr) * 64);
            f32x4 z4 = (f32x4){0.f, 0.f, 0.f, 0.f};
            f32x4 e = __builtin_amdgcn_mfma_f32_16x16x32_bf16(aK, bQ, z4, 0, 0, 0);
#pragma unroll
            for (int r = 0; r < 4; ++r) {
                float p = __expf(fminf(e[r], 80.f));
                Plds[qk_jf * 16 + lg * 4 + r][qk_if * 16 + lr] = f2bf(p);
            }
        }
        __syncthreads();
        {   // phase 2: acc[j 16 x c 128] += P^T(16x32) @ vs(32x128)
            bf8 aP = *(const bf8*)pvA;
#pragma unroll
            for (int cf = 0; cf < 8; ++cf) {
                bf8 bV = *(const bf8*)(vbase + (size_t)cf * 16 * 4096 + i0);
                acc[cf] = __builtin_amdgcn_mfma_f32_16x16x32_bf16(aP, bV, acc[cf], 0, 0, 0);
            }
        }
        __syncthreads();
    }

    const float gamma = *gammaPtr;
#pragma unroll
    for (int cf = 0; cf < 8; ++cf) {
        int c = pv_wc * 128 + cf * 16 + lr;
#pragma unroll
        for (int r = 0; r < 4; ++r) {
            size_t idx = ((size_t)(b * 4096 + j0 + pv_wj * 16 + lg * 4 + r)) * 256 + c;
            out[idx] = gamma * acc[cf][r] + x[idx];
        }
    }
}

extern "C" void kernel_launch(void* const* d_in, const int* in_sizes, int n_in,
                              void* d_out, int out_size, void* d_ws, size_t ws_size,
                              hipStream_t stream)
{
    const float* x  = (const float*)d_in[0];
    const float* Wq = (const float*)d_in[1];
    const float* bq = (const float*)d_in[2];
    const float* Wk = (const float*)d_in[3];
    const float* bk = (const float*)d_in[4];
    const float* Wv = (const float*)d_in[5];
    const float* bv = (const float*)d_in[6];
    const float* gm = (const float*)d_in[7];
    float* out = (float*)d_out;

    char* wsb = (char*)d_ws;
    short* qkb   = (short*)(wsb);
    short* vT    = (short*)(wsb + (2u << 20));
    short* wallT = (short*)(wsb + (10u << 20));
    float* ball  = (float*)(wsb + (10u << 20) + 163840);
    float* zpart = (float*)(wsb + (10u << 20) + 163840 + 1280);
    float* rz    = (float*)(wsb + (10u << 20) + 163840 + 1280 + 262144);

    pack_weights<<<320, 256, 0, stream>>>(Wq, Wk, Wv, bq, bk, bv, wallT, ball);
    qkv_gemm<<<256, 256, 0, stream>>>(x, wallT, ball, qkb, vT);
    zsum_kernel<<<dim3(64, 4, 4), 256, 0, stream>>>(qkb, zpart);
    zfinish<<<64, 256, 0, stream>>>(zpart, rz);
    vscale<<<2048, 256, 0, stream>>>(vT, rz);
    attn_out<<<dim3(64, 4), 512, 0, stream>>>(qkb, vT, x, gm, out);
}

// Round 2
// 216.031 us; speedup vs baseline: 1.7367x; 1.7367x over previous
//
#include <hip/hip_runtime.h>
#include <hip/hip_bf16.h>

// B=4, H=W=64 -> N=4096, C=256, d=32
// ws layout (bytes):
//   qk    [B*N][64] bf16            @ 0        (2 MB)   cols 0..31 q, 32..63 k
//   vT    [B][C][N] bf16            @ 2 MB     (8 MB)   v transposed, scaled by 1/Z by vscale
//   wallT [320][256] bf16           @ 10 MB    (160 KB) packed W^T (q|k|v)
//   ball  [320] f32                 @ +163840  (1.25 KB)
//   zpart [4][B*N] f32              @ +1280    (256 KB)
//   rz    [B*N] f32                 @ +262144  (64 KB)

typedef __attribute__((ext_vector_type(4)))  float    f32x4;
typedef __attribute__((ext_vector_type(16))) float    f32x16;
typedef __attribute__((ext_vector_type(8)))  short    bf8;
typedef __attribute__((ext_vector_type(4)))  short    bf4;
typedef __attribute__((ext_vector_type(4)))  unsigned u32x4;

__device__ __forceinline__ short f2bf(float f) {
    unsigned u = __builtin_bit_cast(unsigned, f);
    u += 0x7FFF + ((u >> 16) & 1);           // RNE
    return (short)(u >> 16);
}
__device__ __forceinline__ float bf2f(short h) {
    unsigned u = ((unsigned)(unsigned short)h) << 16;
    return __builtin_bit_cast(float, u);
}
__device__ __forceinline__ unsigned cvtpk(float lo, float hi) {
    unsigned r;
    asm("v_cvt_pk_bf16_f32 %0, %1, %2" : "=v"(r) : "v"(lo), "v"(hi));
    return r;
}
__device__ __forceinline__ f32x16 z16() {
    f32x16 v;
#pragma unroll
    for (int i = 0; i < 16; ++i) v[i] = 0.f;
    return v;
}

// ---------------- K1: pack weights into B^T (n-major, k-contiguous) bf16 ----
__global__ __launch_bounds__(256) void pack_weights(
    const float* __restrict__ Wq, const float* __restrict__ Wk,
    const float* __restrict__ Wv, const float* __restrict__ bq,
    const float* __restrict__ bk, const float* __restrict__ bv,
    short* __restrict__ wallT, float* __restrict__ ball)
{
    int n = blockIdx.x;        // 0..319
    int k = threadIdx.x;       // 0..255
    float w;
    if (n < 32)       w = Wq[k * 32 + n];
    else if (n < 64)  w = Wk[k * 32 + (n - 32)];
    else              w = Wv[k * 256 + (n - 64)];
    wallT[n * 256 + k] = f2bf(w);
    if (k == 0) ball[n] = (n < 32) ? bq[n] : (n < 64) ? bk[n - 32] : bv[n - 64];
}

// ---------------- K2: QKV projection GEMM [16384,256] x [256,320] -----------
__global__ __launch_bounds__(256) void qkv_gemm(
    const float* __restrict__ x, const short* __restrict__ wallT,
    const float* __restrict__ ball,
    short* __restrict__ qk, short* __restrict__ vT)
{
    const int w  = threadIdx.x >> 6;
    const int l  = threadIdx.x & 63;
    const int lr = l & 15;             // A row / B col within fragment
    const int lg = l >> 4;             // k-group
    const int m0 = blockIdx.x * 64 + w * 16;

    f32x4 acc[20];
#pragma unroll
    for (int i = 0; i < 20; ++i) acc[i] = (f32x4){0.f, 0.f, 0.f, 0.f};

    const float* xrow  = x + (size_t)(m0 + lr) * 256 + lg * 8;
    const short* wbase = wallT + lr * 256 + lg * 8;

#pragma unroll
    for (int ks = 0; ks < 256; ks += 32) {
        f32x4 a0 = *(const f32x4*)(xrow + ks);
        f32x4 a1 = *(const f32x4*)(xrow + ks + 4);
        bf8 af;
#pragma unroll
        for (int t = 0; t < 4; ++t) { af[t] = f2bf(a0[t]); af[t + 4] = f2bf(a1[t]); }
#pragma unroll
        for (int nf = 0; nf < 20; ++nf) {
            bf8 bfr = *(const bf8*)(wbase + nf * 4096 + ks);
            acc[nf] = __builtin_amdgcn_mfma_f32_16x16x32_bf16(af, bfr, acc[nf], 0, 0, 0);
        }
    }

    const int b    = m0 >> 12;
    const int pix0 = (m0 & 4095) + lg * 4;
#pragma unroll
    for (int nf = 0; nf < 20; ++nf) {
        int n = nf * 16 + lr;
        float bias = ball[n];
        if (n < 64) {
#pragma unroll
            for (int r = 0; r < 4; ++r) {
                int m = m0 + lg * 4 + r;
                qk[(size_t)m * 64 + n] = f2bf(acc[nf][r] + bias);
            }
        } else {
            bf4 pv;
#pragma unroll
            for (int r = 0; r < 4; ++r) pv[r] = f2bf(acc[nf][r] + bias);
            *(bf4*)(vT + (size_t)b * 1048576 + (size_t)(n - 64) * 4096 + pix0) = pv;
        }
    }
}

// ---------------- K3: pass A — Z_i = sum_j exp(q_i . k_j)  (max-free) -------
// 32x32x16 MFMA: S block [32 i x 32 j]; lane col = j, regs = i. 4 waves split j.
__global__ __launch_bounds__(256) void zsum_kernel(
    const short* __restrict__ qk, float* __restrict__ zpart)
{
    const int l = threadIdx.x & 63, w = threadIdx.x >> 6;
    const int lr = l & 31, hi = l >> 5;
    const int b  = blockIdx.y;
    const int i0 = blockIdx.x * 32;

    const short* qrow = qk + (size_t)(b * 4096 + i0 + lr) * 64 + hi * 8;
    bf8 q0 = *(const bf8*)(qrow);
    bf8 q1 = *(const bf8*)(qrow + 16);

    float zacc[16];
#pragma unroll
    for (int r = 0; r < 16; ++r) zacc[r] = 0.f;

    const short* kbase = qk + (size_t)(b * 4096 + w * 1024 + lr) * 64 + 32 + hi * 8;
    for (int js = 0; js < 1024; js += 32) {
        bf8 k0 = *(const bf8*)(kbase + (size_t)js * 64);
        bf8 k1 = *(const bf8*)(kbase + (size_t)js * 64 + 16);
        f32x16 S = z16();
        S = __builtin_amdgcn_mfma_f32_32x32x16_bf16(q0, k0, S, 0, 0, 0);
        S = __builtin_amdgcn_mfma_f32_32x32x16_bf16(q1, k1, S, 0, 0, 0);
#pragma unroll
        for (int r = 0; r < 16; ++r) zacc[r] += __expf(fminf(S[r], 80.f));
    }
#pragma unroll
    for (int r = 0; r < 16; ++r) {
        float z = zacc[r];
        z += __shfl_xor(z, 1);  z += __shfl_xor(z, 2);  z += __shfl_xor(z, 4);
        z += __shfl_xor(z, 8);  z += __shfl_xor(z, 16);
        if (lr == 0)
            zpart[(size_t)w * 16384 + b * 4096 + i0 + (r & 3) + 8 * (r >> 2) + 4 * hi] = z;
    }
}

// ---------------- K3b: rz = 1 / sum(partials) --------------------------------
__global__ __launch_bounds__(256) void zfinish(
    const float* __restrict__ zpart, float* __restrict__ rz)
{
    int i = blockIdx.x * 256 + threadIdx.x;   // 0..16383
    float z = zpart[i] + zpart[16384 + i] + zpart[32768 + i] + zpart[49152 + i];
    rz[i] = 1.0f / z;
}

// ---------------- K4: vs = v / Z  (in place on vT, i-contiguous) ------------
__global__ __launch_bounds__(256) void vscale(
    short* __restrict__ vT, const float* __restrict__ rz)
{
    int t = blockIdx.x * 256 + threadIdx.x;
    size_t base = (size_t)t * 8;                // flat element idx into [B*C*N]
    int b = (int)(base >> 20);
    int i = (int)(base & 4095);
    bf8 v = *(bf8*)(vT + base);
    const float* rzp = rz + b * 4096 + i;
#pragma unroll
    for (int e = 0; e < 8; ++e) v[e] = f2bf(bf2f(v[e]) * rzp[e]);
    *(bf8*)(vT + base) = v;
}

// ---------------- K5: register-flash attn_out --------------------------------
// Block: j-tile 32 x full C=256, 8 waves; wave w streams i in {w*32 + t*256}.
// Per 32-i step: S = mfma32(Q,K) (j on lanes, i on regs) -> exp -> cvt_pk +
// permlane32_swap -> 2 PV A-frags in-register -> 16 PV mfma into acc[8] f32x16.
// No LDS / barriers in main loop; one cross-wave LDS reduction at the end.
__global__ __launch_bounds__(512, 2) void attn_out(
    const short* __restrict__ qk, const short* __restrict__ vT,
    const float* __restrict__ x, const float* __restrict__ gammaPtr,
    float* __restrict__ out)
{
    __shared__ float red[8][32][32];           // 32 KB, epilogue only
    const int l = threadIdx.x & 63, w = threadIdx.x >> 6;
    const int lr = l & 31, hi = l >> 5;

    // bijective XCD swizzle: 512 blocks = 8 XCDs x 64; each XCD sees one b.
    int nb = (blockIdx.x & 7) * 64 + (blockIdx.x >> 3);
    const int b = nb >> 7, jt = nb & 127;
    const int j0 = jt * 32;

    // persistent K B-frags (col j = j0+lr, k = d)
    const short* kbase = qk + (size_t)(b * 4096 + j0 + lr) * 64 + 32 + hi * 8;
    bf8 kf0 = *(const bf8*)(kbase);
    bf8 kf1 = *(const bf8*)(kbase + 16);

    f32x16 acc[8];
#pragma unroll
    for (int cf = 0; cf < 8; ++cf) acc[cf] = z16();

    const short* qbase = qk + (size_t)(b * 4096 + lr) * 64 + hi * 8;
    const short* vbase = vT + ((size_t)b << 20) + (size_t)lr * 4096 + hi * 8;

    for (int t = 0; t < 16; ++t) {
        const int ib = w * 32 + t * 256;
        // QK^T: A = Q (rows i = ib+lr), B = K (cols j)
        bf8 q0 = *(const bf8*)(qbase + (size_t)ib * 64);
        bf8 q1 = *(const bf8*)(qbase + (size_t)ib * 64 + 16);
        f32x16 S = z16();
        S = __builtin_amdgcn_mfma_f32_32x32x16_bf16(q0, kf0, S, 0, 0, 0);
        S = __builtin_amdgcn_mfma_f32_32x32x16_bf16(q1, kf1, S, 0, 0, 0);

        float p[16];
#pragma unroll
        for (int r = 0; r < 16; ++r) p[r] = __expf(fminf(S[r], 80.f));

        // C-frag (j on lanes, i on regs) -> PV A-frags via cvt_pk + permlane32_swap
        unsigned X0 = cvtpk(p[0],  p[1]),  Y0 = cvtpk(p[4],  p[5]);
        unsigned X1 = cvtpk(p[2],  p[3]),  Y1 = cvtpk(p[6],  p[7]);
        unsigned X2 = cvtpk(p[8],  p[9]),  Y2 = cvtpk(p[12], p[13]);
        unsigned X3 = cvtpk(p[10], p[11]), Y3 = cvtpk(p[14], p[15]);
        asm("v_permlane32_swap_b32 %0, %1" : "+v"(X0), "+v"(Y0));
        asm("v_permlane32_swap_b32 %0, %1" : "+v"(X1), "+v"(Y1));
        asm("v_permlane32_swap_b32 %0, %1" : "+v"(X2), "+v"(Y2));
        asm("v_permlane32_swap_b32 %0, %1" : "+v"(X3), "+v"(Y3));
        u32x4 a0w = {X0, X1, Y0, Y1};
        u32x4 a1w = {X2, X3, Y2, Y3};
        bf8 A0 = __builtin_bit_cast(bf8, a0w);
        bf8 A1 = __builtin_bit_cast(bf8, a1w);

        // PV: acc[cf] (j x 32c) += P(32j x 32i) @ Vs(32i x 32c)
        const short* vstep = vbase + ib;
#pragma unroll
        for (int cf = 0; cf < 8; ++cf) {
            bf8 v0 = *(const bf8*)(vstep + (size_t)cf * 131072);
            bf8 v1 = *(const bf8*)(vstep + (size_t)cf * 131072 + 16);
            acc[cf] = __builtin_amdgcn_mfma_f32_32x32x16_bf16(A0, v0, acc[cf], 0, 0, 0);
            acc[cf] = __builtin_amdgcn_mfma_f32_32x32x16_bf16(A1, v1, acc[cf], 0, 0, 0);
        }
    }

    // epilogue: cross-wave reduce (8 partials) per 32c chunk, fuse gamma*out + x
    const float gamma = *gammaPtr;
    for (int cf = 0; cf < 8; ++cf) {
        __syncthreads();
#pragma unroll
        for (int r = 0; r < 16; ++r) {
            int jrow = (r & 3) + 8 * (r >> 2) + 4 * hi;
            red[w][jrow][lr] = acc[cf][r];
        }
        __syncthreads();
#pragma unroll
        for (int q = 0; q < 2; ++q) {
            int el = threadIdx.x + q * 512;
            int j = el >> 5, c = el & 31;
            float s = 0.f;
#pragma unroll
            for (int ww = 0; ww < 8; ++ww) s += red[ww][j][c];
            size_t idx = ((size_t)(b * 4096 + j0 + j)) * 256 + cf * 32 + c;
            out[idx] = gamma * s + x[idx];
        }
    }
}

extern "C" void kernel_launch(void* const* d_in, const int* in_sizes, int n_in,
                              void* d_out, int out_size, void* d_ws, size_t ws_size,
                              hipStream_t stream)
{
    const float* x  = (const float*)d_in[0];
    const float* Wq = (const float*)d_in[1];
    const float* bq = (const float*)d_in[2];
    const float* Wk = (const float*)d_in[3];
    const float* bk = (const float*)d_in[4];
    const float* Wv = (const float*)d_in[5];
    const float* bv = (const float*)d_in[6];
    const float* gm = (const float*)d_in[7];
    float* out = (float*)d_out;

    char* wsb = (char*)d_ws;
    short* qkb   = (short*)(wsb);
    short* vT    = (short*)(wsb + (2u << 20));
    short* wallT = (short*)(wsb + (10u << 20));
    float* ball  = (float*)(wsb + (10u << 20) + 163840);
    float* zpart = (float*)(wsb + (10u << 20) + 163840 + 1280);
    float* rz    = (float*)(wsb + (10u << 20) + 163840 + 1280 + 262144);

    pack_weights<<<320, 256, 0, stream>>>(Wq, Wk, Wv, bq, bk, bv, wallT, ball);
    qkv_gemm<<<256, 256, 0, stream>>>(x, wallT, ball, qkb, vT);
    zsum_kernel<<<dim3(128, 4), 256, 0, stream>>>(qkb, zpart);
    zfinish<<<64, 256, 0, stream>>>(zpart, rz);
    vscale<<<2048, 256, 0, stream>>>(vT, rz);
    attn_out<<<512, 512, 0, stream>>>(qkb, vT, x, gm, out);
}

// Round 3
// 174.476 us; speedup vs baseline: 2.1503x; 1.2382x over previous
//
#include <hip/hip_runtime.h>
#include <hip/hip_bf16.h>

// B=4, H=W=64 -> N=4096, C=256, d=32
// All MFMA operands stored FRAGMENT-ORDERED so every load is a coalesced
// 1KB wave-load (lane-contiguous base + l*8 shorts).
//
// qF/kF [b][i>>5][f][lane][8] : lane = (i&31)+32*((d>>3)&1), f = d>>4, e = d&7
//   (A-frag and B-frag layouts coincide for mfma_32x32x16 -> one buffer, both roles)
// vF    [b][i>>4][c>>5][lane][8] : lane = (c&31)+32*((i>>3)&1), e = i&7
// wallF [nf][ks][lane][8] : 16x16x32 B-frags of packed W^T (q|k|v)
//
// ws layout (bytes):
//   qF    @ 0          1 MB
//   kF    @ 1 MB       1 MB
//   vF    @ 2 MB       8 MB
//   wallF @ 10 MB      160 KB
//   ball  @ +163840    1.25 KB
//   zpart @ +1280      256 KB
//   lrz   @ +262144    64 KB

typedef __attribute__((ext_vector_type(4)))  float    f32x4;
typedef __attribute__((ext_vector_type(16))) float    f32x16;
typedef __attribute__((ext_vector_type(8)))  short    bf8;
typedef __attribute__((ext_vector_type(4)))  short    bf4;
typedef __attribute__((ext_vector_type(4)))  unsigned u32x4;

__device__ __forceinline__ short f2bf(float f) {
    unsigned u = __builtin_bit_cast(unsigned, f);
    u += 0x7FFF + ((u >> 16) & 1);           // RNE
    return (short)(u >> 16);
}
__device__ __forceinline__ unsigned cvtpk(float lo, float hi) {
    unsigned r;
    asm("v_cvt_pk_bf16_f32 %0, %1, %2" : "=v"(r) : "v"(lo), "v"(hi));
    return r;
}
__device__ __forceinline__ f32x16 z16() {
    f32x16 v;
#pragma unroll
    for (int i = 0; i < 16; ++i) v[i] = 0.f;
    return v;
}

// ---------------- K1: pack weights into 16x16x32 B-frag order ---------------
__global__ __launch_bounds__(256) void pack_weights(
    const float* __restrict__ Wq, const float* __restrict__ Wk,
    const float* __restrict__ Wv, const float* __restrict__ bq,
    const float* __restrict__ bk, const float* __restrict__ bv,
    short* __restrict__ wallF, float* __restrict__ ball)
{
    int n = blockIdx.x;        // 0..319
    int k = threadIdx.x;       // 0..255
    float w;
    if (n < 32)       w = Wq[k * 32 + n];
    else if (n < 64)  w = Wk[k * 32 + (n - 32)];
    else              w = Wv[k * 256 + (n - 64)];
    int nf = n >> 4, lcol = n & 15;
    int ks = k >> 5, lg = (k >> 3) & 3, e = k & 7;
    wallF[((size_t)(nf * 8 + ks) * 64 + lg * 16 + lcol) * 8 + e] = f2bf(w);
    if (k == 0) ball[n] = (n < 32) ? bq[n] : (n < 64) ? bk[n - 32] : bv[n - 64];
}

// ---------------- K2: QKV projection -> fragment-ordered qF/kF/vF -----------
__global__ __launch_bounds__(256) void qkv_gemm(
    const float* __restrict__ x, const short* __restrict__ wallF,
    const float* __restrict__ ball,
    short* __restrict__ qf, short* __restrict__ kf, short* __restrict__ vf)
{
    const int w  = threadIdx.x >> 6;
    const int l  = threadIdx.x & 63;
    const int lr = l & 15;             // A row / B col within fragment
    const int lg = l >> 4;             // k-group
    const int m0 = blockIdx.x * 64 + w * 16;

    f32x4 acc[20];
#pragma unroll
    for (int i = 0; i < 20; ++i) acc[i] = (f32x4){0.f, 0.f, 0.f, 0.f};

    const float* xrow = x + (size_t)(m0 + lr) * 256 + lg * 8;

#pragma unroll
    for (int ks = 0; ks < 8; ++ks) {
        f32x4 a0 = *(const f32x4*)(xrow + ks * 32);
        f32x4 a1 = *(const f32x4*)(xrow + ks * 32 + 4);
        bf8 af;
#pragma unroll
        for (int t = 0; t < 4; ++t) { af[t] = f2bf(a0[t]); af[t + 4] = f2bf(a1[t]); }
        const short* wb = wallF + (size_t)ks * 512 + l * 8;
#pragma unroll
        for (int nf = 0; nf < 20; ++nf) {
            bf8 bfr = *(const bf8*)(wb + (size_t)nf * 4096);
            acc[nf] = __builtin_amdgcn_mfma_f32_16x16x32_bf16(af, bfr, acc[nf], 0, 0, 0);
        }
    }

    const int b      = m0 >> 12;
    const int i_base = m0 + lg * 4;          // rows i_base..i_base+3
#pragma unroll
    for (int nf = 0; nf < 20; ++nf) {
        int n = nf * 16 + lr;
        float bias = ball[n];
        if (nf < 4) {          // q (nf<2) / k: d = n & 31
            int d = n & 31;
            int f = (d >> 4) & 1, sub = (d >> 3) & 1, e = d & 7;
            short* dst = (nf < 2) ? qf : kf;
            size_t base = ((size_t)(b * 128 + (i_base >> 5)) * 2 + f) * 512 + 256 * sub + e;
#pragma unroll
            for (int r = 0; r < 4; ++r) {
                int i31 = (i_base + r) & 31;
                dst[base + (size_t)i31 * 8] = f2bf(acc[nf][r] + bias);
            }
        } else {               // v: c = n - 64
            int c = n - 64;
            bf4 pv;
#pragma unroll
            for (int r = 0; r < 4; ++r) pv[r] = f2bf(acc[nf][r] + bias);
            size_t addr = (size_t)(b * 256 + (i_base >> 4)) * 4096
                        + (size_t)(c >> 5) * 512
                        + (size_t)((c & 31) + 32 * ((i_base >> 3) & 1)) * 8
                        + (i_base & 7);
            *(bf4*)(vf + addr) = pv;
        }
    }
}

// ---------------- K3: Z_i = sum_j exp(q_i . k_j), swapped operands ----------
// S = mfma(A=K rows j, B=Q cols i): i on lanes, j on regs -> j-reduce in-lane.
__global__ __launch_bounds__(256) void zsum_kernel(
    const short* __restrict__ qF, const short* __restrict__ kF,
    float* __restrict__ zpart)
{
    const int l = threadIdx.x & 63, w = threadIdx.x >> 6;
    const int b = blockIdx.y;
    const int itile = blockIdx.x;            // 0..127

    const short* qp = qF + (size_t)(b * 128 + itile) * 1024 + l * 8;
    bf8 qb0 = *(const bf8*)(qp);
    bf8 qb1 = *(const bf8*)(qp + 512);

    float zacc = 0.f;
    const short* kbase = kF + (size_t)b * 131072 + (size_t)w * 32768 + l * 8;
    for (int jt = 0; jt < 32; ++jt) {
        const short* kp = kbase + jt * 1024;
        bf8 kA0 = *(const bf8*)(kp);
        bf8 kA1 = *(const bf8*)(kp + 512);
        f32x16 S = z16();
        S = __builtin_amdgcn_mfma_f32_32x32x16_bf16(kA0, qb0, S, 0, 0, 0);
        S = __builtin_amdgcn_mfma_f32_32x32x16_bf16(kA1, qb1, S, 0, 0, 0);
#pragma unroll
        for (int r = 0; r < 16; ++r) zacc += __expf(fminf(S[r], 80.f));
    }
    zacc += __shfl_xor(zacc, 32);
    if (l < 32)
        zpart[(size_t)w * 16384 + b * 4096 + itile * 32 + l] = zacc;
}

// ---------------- K3b: lrz = -log(sum of partials) ---------------------------
__global__ __launch_bounds__(256) void zfinish(
    const float* __restrict__ zpart, float* __restrict__ lrz)
{
    int i = blockIdx.x * 256 + threadIdx.x;   // 0..16383
    float z = zpart[i] + zpart[16384 + i] + zpart[32768 + i] + zpart[49152 + i];
    lrz[i] = -__logf(z);
}

// ---------------- K5: out = gamma * (P^T @ V) + x ----------------------------
// Grid 256 = (128 j-tiles of 128) x (2 c-halves); 8 waves = (wj 0..3, wc 0..1).
// Wave owns j 32 x c 64; streams all 4096 i; softmax in-register (swapped-QK
// C-frag -> cvt_pk + permlane32_swap -> PV A-frags); 1/Z folded via lrz.
__global__ __launch_bounds__(512) void attn_out(
    const short* __restrict__ qF, const short* __restrict__ kF,
    const short* __restrict__ vF, const float* __restrict__ lrz,
    const float* __restrict__ x, const float* __restrict__ gammaPtr,
    float* __restrict__ out)
{
    const int l = threadIdx.x & 63, w = threadIdx.x >> 6;
    const int lr = l & 31, hi = l >> 5;
    const int wj = w & 3, wc = w >> 2;

    // XCD swizzle: 256 blocks -> 32 consecutive per XCD; 2 XCDs share one b.
    int nb = (blockIdx.x & 7) * 32 + (blockIdx.x >> 3);
    const int jt = nb >> 1, ch = nb & 1;
    const int b = jt >> 5, j0 = (jt & 31) * 128;

    const int jtile = (j0 >> 5) + wj;
    const short* kfp = kF + (size_t)(b * 128 + jtile) * 1024 + l * 8;
    bf8 kf0 = *(const bf8*)(kfp);
    bf8 kf1 = *(const bf8*)(kfp + 512);

    const int c0 = ch * 128 + wc * 64;

    f32x16 acc0 = z16(), acc1 = z16();

    const short* qbase = qF + (size_t)b * 131072 + l * 8;
    const short* vbase = vF + (size_t)b * 1048576 + (size_t)(c0 >> 5) * 512 + l * 8;
    const float* lzb   = lrz + b * 4096 + 4 * hi;

    for (int t = 0; t < 128; ++t) {
        const short* qp = qbase + t * 1024;
        bf8 q0 = *(const bf8*)(qp);
        bf8 q1 = *(const bf8*)(qp + 512);

        f32x16 S = z16();
        S = __builtin_amdgcn_mfma_f32_32x32x16_bf16(q0, kf0, S, 0, 0, 0);
        S = __builtin_amdgcn_mfma_f32_32x32x16_bf16(q1, kf1, S, 0, 0, 0);

        const float* lzt = lzb + t * 32;
        f32x4 lz0 = *(const f32x4*)(lzt);
        f32x4 lz1 = *(const f32x4*)(lzt + 8);
        f32x4 lz2 = *(const f32x4*)(lzt + 16);
        f32x4 lz3 = *(const f32x4*)(lzt + 24);

        float p[16];
#pragma unroll
        for (int r = 0; r < 16; ++r) {
            float lz = (r < 4) ? lz0[r & 3] : (r < 8) ? lz1[r & 3]
                     : (r < 12) ? lz2[r & 3] : lz3[r & 3];
            p[r] = __expf(fminf(S[r], 80.f) + lz);    // == exp(e)/Z, <= 1
        }

        // C-frag (j on lanes, i on regs) -> PV A-frags (j on lanes, i on elems)
        unsigned X0 = cvtpk(p[0],  p[1]),  Y0 = cvtpk(p[4],  p[5]);
        unsigned X1 = cvtpk(p[2],  p[3]),  Y1 = cvtpk(p[6],  p[7]);
        unsigned X2 = cvtpk(p[8],  p[9]),  Y2 = cvtpk(p[12], p[13]);
        unsigned X3 = cvtpk(p[10], p[11]), Y3 = cvtpk(p[14], p[15]);
        asm("v_permlane32_swap_b32 %0, %1" : "+v"(X0), "+v"(Y0));
        asm("v_permlane32_swap_b32 %0, %1" : "+v"(X1), "+v"(Y1));
        asm("v_permlane32_swap_b32 %0, %1" : "+v"(X2), "+v"(Y2));
        asm("v_permlane32_swap_b32 %0, %1" : "+v"(X3), "+v"(Y3));
        u32x4 a0w = {X0, X1, Y0, Y1};
        u32x4 a1w = {X2, X3, Y2, Y3};
        bf8 A0 = __builtin_bit_cast(bf8, a0w);
        bf8 A1 = __builtin_bit_cast(bf8, a1w);

        const short* vp = vbase + (size_t)t * 8192;   // i-tile 2t
        bf8 v00 = *(const bf8*)(vp);
        bf8 v01 = *(const bf8*)(vp + 4096);
        bf8 v10 = *(const bf8*)(vp + 512);
        bf8 v11 = *(const bf8*)(vp + 4096 + 512);

        acc0 = __builtin_amdgcn_mfma_f32_32x32x16_bf16(A0, v00, acc0, 0, 0, 0);
        acc0 = __builtin_amdgcn_mfma_f32_32x32x16_bf16(A1, v01, acc0, 0, 0, 0);
        acc1 = __builtin_amdgcn_mfma_f32_32x32x16_bf16(A0, v10, acc1, 0, 0, 0);
        acc1 = __builtin_amdgcn_mfma_f32_32x32x16_bf16(A1, v11, acc1, 0, 0, 0);
    }

    const float gamma = *gammaPtr;
#pragma unroll
    for (int r = 0; r < 16; ++r) {
        int j = j0 + wj * 32 + (r & 3) + 8 * (r >> 2) + 4 * hi;
        size_t idx = (size_t)(b * 4096 + j) * 256 + c0 + lr;
        out[idx]      = gamma * acc0[r] + x[idx];
        out[idx + 32] = gamma * acc1[r] + x[idx + 32];
    }
}

extern "C" void kernel_launch(void* const* d_in, const int* in_sizes, int n_in,
                              void* d_out, int out_size, void* d_ws, size_t ws_size,
                              hipStream_t stream)
{
    const float* x  = (const float*)d_in[0];
    const float* Wq = (const float*)d_in[1];
    const float* bq = (const float*)d_in[2];
    const float* Wk = (const float*)d_in[3];
    const float* bk = (const float*)d_in[4];
    const float* Wv = (const float*)d_in[5];
    const float* bv = (const float*)d_in[6];
    const float* gm = (const float*)d_in[7];
    float* out = (float*)d_out;

    char* wsb = (char*)d_ws;
    short* qf    = (short*)(wsb);
    short* kf    = (short*)(wsb + (1u << 20));
    short* vf    = (short*)(wsb + (2u << 20));
    short* wallF = (short*)(wsb + (10u << 20));
    float* ball  = (float*)(wsb + (10u << 20) + 163840);
    float* zpart = (float*)(wsb + (10u << 20) + 163840 + 1280);
    float* lrz   = (float*)(wsb + (10u << 20) + 163840 + 1280 + 262144);

    pack_weights<<<320, 256, 0, stream>>>(Wq, Wk, Wv, bq, bk, bv, wallF, ball);
    qkv_gemm<<<256, 256, 0, stream>>>(x, wallF, ball, qf, kf, vf);
    zsum_kernel<<<dim3(128, 4), 256, 0, stream>>>(qf, kf, zpart);
    zfinish<<<64, 256, 0, stream>>>(zpart, lrz);
    attn_out<<<256, 512, 0, stream>>>(qf, kf, vf, lrz, x, gm, out);
}

// Round 4
// 174.163 us; speedup vs baseline: 2.1542x; 1.0018x over previous
//
#include <hip/hip_runtime.h>
#include <hip/hip_bf16.h>

// B=4, H=W=64 -> N=4096, C=256, d=32
// All MFMA operands stored FRAGMENT-ORDERED so every load is a coalesced
// 1KB wave-load (lane-contiguous base + l*8 shorts).
//
// qF/kF [b][i>>5][f][lane][8] : lane = (i&31)+32*((d>>3)&1), f = d>>4, e = d&7
//   (A-frag and B-frag layouts coincide for mfma_32x32x16 -> one buffer, both roles)
// vF    [b][i>>4][c>>5][lane][8] : lane = (c&31)+32*((i>>3)&1), e = i&7
// wallF [nf][ks][lane][8] : 16x16x32 B-frags of packed W^T (q|k|v)
//
// ws layout (bytes):
//   qF    @ 0          1 MB
//   kF    @ 1 MB       1 MB
//   vF    @ 2 MB       8 MB
//   wallF @ 10 MB      160 KB
//   ball  @ +163840    1.25 KB
//   zpart @ +1280      256 KB
//   lrz   @ +262144    64 KB

typedef __attribute__((ext_vector_type(4)))  float    f32x4;
typedef __attribute__((ext_vector_type(16))) float    f32x16;
typedef __attribute__((ext_vector_type(8)))  short    bf8;
typedef __attribute__((ext_vector_type(4)))  short    bf4;
typedef __attribute__((ext_vector_type(4)))  unsigned u32x4;

__device__ __forceinline__ short f2bf(float f) {
    unsigned u = __builtin_bit_cast(unsigned, f);
    u += 0x7FFF + ((u >> 16) & 1);           // RNE
    return (short)(u >> 16);
}
__device__ __forceinline__ unsigned cvtpk(float lo, float hi) {
    unsigned r;
    asm("v_cvt_pk_bf16_f32 %0, %1, %2" : "=v"(r) : "v"(lo), "v"(hi));
    return r;
}
__device__ __forceinline__ f32x16 z16() {
    f32x16 v;
#pragma unroll
    for (int i = 0; i < 16; ++i) v[i] = 0.f;
    return v;
}

// ---------------- K1: pack weights into 16x16x32 B-frag order ---------------
__global__ __launch_bounds__(256) void pack_weights(
    const float* __restrict__ Wq, const float* __restrict__ Wk,
    const float* __restrict__ Wv, const float* __restrict__ bq,
    const float* __restrict__ bk, const float* __restrict__ bv,
    short* __restrict__ wallF, float* __restrict__ ball)
{
    int n = blockIdx.x;        // 0..319
    int k = threadIdx.x;       // 0..255
    float w;
    if (n < 32)       w = Wq[k * 32 + n];
    else if (n < 64)  w = Wk[k * 32 + (n - 32)];
    else              w = Wv[k * 256 + (n - 64)];
    int nf = n >> 4, lcol = n & 15;
    int ks = k >> 5, lg = (k >> 3) & 3, e = k & 7;
    wallF[((size_t)(nf * 8 + ks) * 64 + lg * 16 + lcol) * 8 + e] = f2bf(w);
    if (k == 0) ball[n] = (n < 32) ? bq[n] : (n < 64) ? bk[n - 32] : bv[n - 64];
}

// ---------------- K2: QKV projection -> fragment-ordered qF/kF/vF -----------
__global__ __launch_bounds__(256) void qkv_gemm(
    const float* __restrict__ x, const short* __restrict__ wallF,
    const float* __restrict__ ball,
    short* __restrict__ qf, short* __restrict__ kf, short* __restrict__ vf)
{
    const int w  = threadIdx.x >> 6;
    const int l  = threadIdx.x & 63;
    const int lr = l & 15;             // A row / B col within fragment
    const int lg = l >> 4;             // k-group
    const int m0 = blockIdx.x * 64 + w * 16;

    f32x4 acc[20];
#pragma unroll
    for (int i = 0; i < 20; ++i) acc[i] = (f32x4){0.f, 0.f, 0.f, 0.f};

    const float* xrow = x + (size_t)(m0 + lr) * 256 + lg * 8;

#pragma unroll
    for (int ks = 0; ks < 8; ++ks) {
        f32x4 a0 = *(const f32x4*)(xrow + ks * 32);
        f32x4 a1 = *(const f32x4*)(xrow + ks * 32 + 4);
        bf8 af;
#pragma unroll
        for (int t = 0; t < 4; ++t) { af[t] = f2bf(a0[t]); af[t + 4] = f2bf(a1[t]); }
        const short* wb = wallF + (size_t)ks * 512 + l * 8;
#pragma unroll
        for (int nf = 0; nf < 20; ++nf) {
            bf8 bfr = *(const bf8*)(wb + (size_t)nf * 4096);
            acc[nf] = __builtin_amdgcn_mfma_f32_16x16x32_bf16(af, bfr, acc[nf], 0, 0, 0);
        }
    }

    const int b      = m0 >> 12;
    const int i_base = m0 + lg * 4;          // rows i_base..i_base+3
#pragma unroll
    for (int nf = 0; nf < 20; ++nf) {
        int n = nf * 16 + lr;
        float bias = ball[n];
        if (nf < 4) {          // q (nf<2) / k: d = n & 31
            int d = n & 31;
            int f = (d >> 4) & 1, sub = (d >> 3) & 1, e = d & 7;
            short* dst = (nf < 2) ? qf : kf;
            size_t base = ((size_t)(b * 128 + (i_base >> 5)) * 2 + f) * 512 + 256 * sub + e;
#pragma unroll
            for (int r = 0; r < 4; ++r) {
                int i31 = (i_base + r) & 31;
                dst[base + (size_t)i31 * 8] = f2bf(acc[nf][r] + bias);
            }
        } else {               // v: c = n - 64
            int c = n - 64;
            bf4 pv;
#pragma unroll
            for (int r = 0; r < 4; ++r) pv[r] = f2bf(acc[nf][r] + bias);
            size_t addr = (size_t)(b * 256 + (i_base >> 4)) * 4096
                        + (size_t)(c >> 5) * 512
                        + (size_t)((c & 31) + 32 * ((i_base >> 3) & 1)) * 8
                        + (i_base & 7);
            *(bf4*)(vf + addr) = pv;
        }
    }
}

// ---------------- K3: Z_i = sum_j exp(q_i . k_j), swapped operands ----------
// S = mfma(A=K rows j, B=Q cols i): i on lanes, j on regs -> j-reduce in-lane.
__global__ __launch_bounds__(256) void zsum_kernel(
    const short* __restrict__ qF, const short* __restrict__ kF,
    float* __restrict__ zpart)
{
    const int l = threadIdx.x & 63, w = threadIdx.x >> 6;
    const int b = blockIdx.y;
    const int itile = blockIdx.x;            // 0..127

    const short* qp = qF + (size_t)(b * 128 + itile) * 1024 + l * 8;
    bf8 qb0 = *(const bf8*)(qp);
    bf8 qb1 = *(const bf8*)(qp + 512);

    float zacc = 0.f;
    const short* kbase = kF + (size_t)b * 131072 + (size_t)w * 32768 + l * 8;
    for (int jt = 0; jt < 32; ++jt) {
        const short* kp = kbase + jt * 1024;
        bf8 kA0 = *(const bf8*)(kp);
        bf8 kA1 = *(const bf8*)(kp + 512);
        f32x16 S = z16();
        S = __builtin_amdgcn_mfma_f32_32x32x16_bf16(kA0, qb0, S, 0, 0, 0);
        S = __builtin_amdgcn_mfma_f32_32x32x16_bf16(kA1, qb1, S, 0, 0, 0);
#pragma unroll
        for (int r = 0; r < 16; ++r) zacc += __expf(fminf(S[r], 80.f));
    }
    zacc += __shfl_xor(zacc, 32);
    if (l < 32)
        zpart[(size_t)w * 16384 + b * 4096 + itile * 32 + l] = zacc;
}

// ---------------- K3b: lrz = -log(sum of partials) ---------------------------
__global__ __launch_bounds__(256) void zfinish(
    const float* __restrict__ zpart, float* __restrict__ lrz)
{
    int i = blockIdx.x * 256 + threadIdx.x;   // 0..16383
    float z = zpart[i] + zpart[16384 + i] + zpart[32768 + i] + zpart[49152 + i];
    lrz[i] = -__logf(z);
}

// ---------------- K5: out = gamma * (P^T @ V) + x ----------------------------
// Grid 256 = (128 j-tiles of 128) x (2 c-halves); 8 waves = (wj 0..3, wc 0..1).
// Wave owns j 32 x c 64; streams all 4096 i; softmax in-register (swapped-QK
// C-frag -> cvt_pk + permlane32_swap -> PV A-frags); 1/Z folded via lrz.
__global__ __launch_bounds__(512) void attn_out(
    const short* __restrict__ qF, const short* __restrict__ kF,
    const short* __restrict__ vF, const float* __restrict__ lrz,
    const float* __restrict__ x, const float* __restrict__ gammaPtr,
    float* __restrict__ out)
{
    const int l = threadIdx.x & 63, w = threadIdx.x >> 6;
    const int lr = l & 31, hi = l >> 5;
    const int wj = w & 3, wc = w >> 2;

    // XCD swizzle: 256 blocks -> 32 consecutive per XCD; 2 XCDs share one b.
    int nb = (blockIdx.x & 7) * 32 + (blockIdx.x >> 3);
    const int jt = nb >> 1, ch = nb & 1;
    const int b = jt >> 5, j0 = (jt & 31) * 128;

    const int jtile = (j0 >> 5) + wj;
    const short* kfp = kF + (size_t)(b * 128 + jtile) * 1024 + l * 8;
    bf8 kf0 = *(const bf8*)(kfp);
    bf8 kf1 = *(const bf8*)(kfp + 512);

    const int c0 = ch * 128 + wc * 64;

    f32x16 acc0 = z16(), acc1 = z16();

    const short* qbase = qF + (size_t)b * 131072 + l * 8;
    const short* vbase = vF + (size_t)b * 1048576 + (size_t)(c0 >> 5) * 512 + l * 8;
    const float* lzb   = lrz + b * 4096 + 4 * hi;

    for (int t = 0; t < 128; ++t) {
        const short* qp = qbase + t * 1024;
        bf8 q0 = *(const bf8*)(qp);
        bf8 q1 = *(const bf8*)(qp + 512);

        f32x16 S = z16();
        S = __builtin_amdgcn_mfma_f32_32x32x16_bf16(q0, kf0, S, 0, 0, 0);
        S = __builtin_amdgcn_mfma_f32_32x32x16_bf16(q1, kf1, S, 0, 0, 0);

        const float* lzt = lzb + t * 32;
        f32x4 lz0 = *(const f32x4*)(lzt);
        f32x4 lz1 = *(const f32x4*)(lzt + 8);
        f32x4 lz2 = *(const f32x4*)(lzt + 16);
        f32x4 lz3 = *(const f32x4*)(lzt + 24);

        float p[16];
#pragma unroll
        for (int r = 0; r < 16; ++r) {
            float lz = (r < 4) ? lz0[r & 3] : (r < 8) ? lz1[r & 3]
                     : (r < 12) ? lz2[r & 3] : lz3[r & 3];
            p[r] = __expf(fminf(S[r], 80.f) + lz);    // == exp(e)/Z, <= 1
        }

        // C-frag (j on lanes, i on regs) -> PV A-frags (j on lanes, i on elems)
        unsigned X0 = cvtpk(p[0],  p[1]),  Y0 = cvtpk(p[4],  p[5]);
        unsigned X1 = cvtpk(p[2],  p[3]),  Y1 = cvtpk(p[6],  p[7]);
        unsigned X2 = cvtpk(p[8],  p[9]),  Y2 = cvtpk(p[12], p[13]);
        unsigned X3 = cvtpk(p[10], p[11]), Y3 = cvtpk(p[14], p[15]);
        asm("v_permlane32_swap_b32 %0, %1" : "+v"(X0), "+v"(Y0));
        asm("v_permlane32_swap_b32 %0, %1" : "+v"(X1), "+v"(Y1));
        asm("v_permlane32_swap_b32 %0, %1" : "+v"(X2), "+v"(Y2));
        asm("v_permlane32_swap_b32 %0, %1" : "+v"(X3), "+v"(Y3));
        u32x4 a0w = {X0, X1, Y0, Y1};
        u32x4 a1w = {X2, X3, Y2, Y3};
        bf8 A0 = __builtin_bit_cast(bf8, a0w);
        bf8 A1 = __builtin_bit_cast(bf8, a1w);

        const short* vp = vbase + (size_t)t * 8192;   // i-tile 2t
        bf8 v00 = *(const bf8*)(vp);
        bf8 v01 = *(const bf8*)(vp + 4096);
        bf8 v10 = *(const bf8*)(vp + 512);
        bf8 v11 = *(const bf8*)(vp + 4096 + 512);

        acc0 = __builtin_amdgcn_mfma_f32_32x32x16_bf16(A0, v00, acc0, 0, 0, 0);
        acc0 = __builtin_amdgcn_mfma_f32_32x32x16_bf16(A1, v01, acc0, 0, 0, 0);
        acc1 = __builtin_amdgcn_mfma_f32_32x32x16_bf16(A0, v10, acc1, 0, 0, 0);
        acc1 = __builtin_amdgcn_mfma_f32_32x32x16_bf16(A1, v11, acc1, 0, 0, 0);
    }

    const float gamma = *gammaPtr;
#pragma unroll
    for (int r = 0; r < 16; ++r) {
        int j = j0 + wj * 32 + (r & 3) + 8 * (r >> 2) + 4 * hi;
        size_t idx = (size_t)(b * 4096 + j) * 256 + c0 + lr;
        out[idx]      = gamma * acc0[r] + x[idx];
        out[idx + 32] = gamma * acc1[r] + x[idx + 32];
    }
}

extern "C" void kernel_launch(void* const* d_in, const int* in_sizes, int n_in,
                              void* d_out, int out_size, void* d_ws, size_t ws_size,
                              hipStream_t stream)
{
    const float* x  = (const float*)d_in[0];
    const float* Wq = (const float*)d_in[1];
    const float* bq = (const float*)d_in[2];
    const float* Wk = (const float*)d_in[3];
    const float* bk = (const float*)d_in[4];
    const float* Wv = (const float*)d_in[5];
    const float* bv = (const float*)d_in[6];
    const float* gm = (const float*)d_in[7];
    float* out = (float*)d_out;

    char* wsb = (char*)d_ws;
    short* qf    = (short*)(wsb);
    short* kf    = (short*)(wsb + (1u << 20));
    short* vf    = (short*)(wsb + (2u << 20));
    short* wallF = (short*)(wsb + (10u << 20));
    float* ball  = (float*)(wsb + (10u << 20) + 163840);
    float* zpart = (float*)(wsb + (10u << 20) + 163840 + 1280);
    float* lrz   = (float*)(wsb + (10u << 20) + 163840 + 1280 + 262144);

    pack_weights<<<320, 256, 0, stream>>>(Wq, Wk, Wv, bq, bk, bv, wallF, ball);
    qkv_gemm<<<256, 256, 0, stream>>>(x, wallF, ball, qf, kf, vf);
    zsum_kernel<<<dim3(128, 4), 256, 0, stream>>>(qf, kf, zpart);
    zfinish<<<64, 256, 0, stream>>>(zpart, lrz);
    attn_out<<<256, 512, 0, stream>>>(qf, kf, vf, lrz, x, gm, out);
}

// Round 5
// 104.977 us; speedup vs baseline: 3.5739x; 1.6591x over previous
//
#include <hip/hip_runtime.h>
#include <hip/hip_bf16.h>

// B=4, H=W=64 -> N=4096, C=256, d=32
// All MFMA operands stored FRAGMENT-ORDERED so every load is a coalesced
// 1KB wave-load (lane-contiguous base + l*8 shorts).
//
// qF/kF [b][i>>5][f][lane][8] : lane = (i&31)+32*((d>>3)&1), f = d>>4, e = d&7
// vF    [b][i>>4][c>>5][lane][8] : lane = (c&31)+32*((i>>3)&1), e = i&7
// wallF [nf][ks][lane][8] : 16x16x32 B-frags of packed W^T (q|k|v)
//
// ws layout (bytes):
//   qF    @ 0          1 MB
//   kF    @ 1 MB       1 MB
//   vF    @ 2 MB       8 MB
//   wallF @ 10 MB      160 KB
//   ball  @ +163840    1.25 KB
//   zpart @ +1280      256 KB
//   rz    @ +262144    64 KB

typedef __attribute__((ext_vector_type(4)))  float    f32x4;
typedef __attribute__((ext_vector_type(16))) float    f32x16;
typedef __attribute__((ext_vector_type(8)))  short    bf8;
typedef __attribute__((ext_vector_type(4)))  short    bf4;
typedef __attribute__((ext_vector_type(4)))  unsigned u32x4;

__device__ __forceinline__ short f2bf(float f) {
    unsigned u = __builtin_bit_cast(unsigned, f);
    u += 0x7FFF + ((u >> 16) & 1);           // RNE
    return (short)(u >> 16);
}
__device__ __forceinline__ float bf2f(short h) {
    unsigned u = ((unsigned)(unsigned short)h) << 16;
    return __builtin_bit_cast(float, u);
}
__device__ __forceinline__ unsigned cvtpk(float lo, float hi) {
    unsigned r;
    asm("v_cvt_pk_bf16_f32 %0, %1, %2" : "=v"(r) : "v"(lo), "v"(hi));
    return r;
}
__device__ __forceinline__ f32x16 z16() {
    f32x16 v;
#pragma unroll
    for (int i = 0; i < 16; ++i) v[i] = 0.f;
    return v;
}

// ---------------- K1: pack weights into 16x16x32 B-frag order ---------------
__global__ __launch_bounds__(256) void pack_weights(
    const float* __restrict__ Wq, const float* __restrict__ Wk,
    const float* __restrict__ Wv, const float* __restrict__ bq,
    const float* __restrict__ bk, const float* __restrict__ bv,
    short* __restrict__ wallF, float* __restrict__ ball)
{
    int n = blockIdx.x;        // 0..319
    int k = threadIdx.x;       // 0..255
    float w;
    if (n < 32)       w = Wq[k * 32 + n];
    else if (n < 64)  w = Wk[k * 32 + (n - 32)];
    else              w = Wv[k * 256 + (n - 64)];
    int nf = n >> 4, lcol = n & 15;
    int ks = k >> 5, lg = (k >> 3) & 3, e = k & 7;
    wallF[((size_t)(nf * 8 + ks) * 64 + lg * 16 + lcol) * 8 + e] = f2bf(w);
    if (k == 0) ball[n] = (n < 32) ? bq[n] : (n < 64) ? bk[n - 32] : bv[n - 64];
}

// ---------------- K2: QKV projection -> fragment-ordered qF/kF/vF -----------
__global__ __launch_bounds__(256) void qkv_gemm(
    const float* __restrict__ x, const short* __restrict__ wallF,
    const float* __restrict__ ball,
    short* __restrict__ qf, short* __restrict__ kf, short* __restrict__ vf)
{
    const int w  = threadIdx.x >> 6;
    const int l  = threadIdx.x & 63;
    const int lr = l & 15;             // A row / B col within fragment
    const int lg = l >> 4;             // k-group
    const int m0 = blockIdx.x * 64 + w * 16;

    f32x4 acc[20];
#pragma unroll
    for (int i = 0; i < 20; ++i) acc[i] = (f32x4){0.f, 0.f, 0.f, 0.f};

    const float* xrow = x + (size_t)(m0 + lr) * 256 + lg * 8;

#pragma unroll
    for (int ks = 0; ks < 8; ++ks) {
        f32x4 a0 = *(const f32x4*)(xrow + ks * 32);
        f32x4 a1 = *(const f32x4*)(xrow + ks * 32 + 4);
        bf8 af;
#pragma unroll
        for (int t = 0; t < 4; ++t) { af[t] = f2bf(a0[t]); af[t + 4] = f2bf(a1[t]); }
        const short* wb = wallF + (size_t)ks * 512 + l * 8;
#pragma unroll
        for (int nf = 0; nf < 20; ++nf) {
            bf8 bfr = *(const bf8*)(wb + (size_t)nf * 4096);
            acc[nf] = __builtin_amdgcn_mfma_f32_16x16x32_bf16(af, bfr, acc[nf], 0, 0, 0);
        }
    }

    const int b      = m0 >> 12;
    const int i_base = m0 + lg * 4;          // rows i_base..i_base+3
#pragma unroll
    for (int nf = 0; nf < 20; ++nf) {
        int n = nf * 16 + lr;
        float bias = ball[n];
        if (nf < 4) {          // q (nf<2) / k: d = n & 31
            int d = n & 31;
            int f = (d >> 4) & 1, sub = (d >> 3) & 1, e = d & 7;
            short* dst = (nf < 2) ? qf : kf;
            size_t base = ((size_t)(b * 128 + (i_base >> 5)) * 2 + f) * 512 + 256 * sub + e;
#pragma unroll
            for (int r = 0; r < 4; ++r) {
                int i31 = (i_base + r) & 31;
                dst[base + (size_t)i31 * 8] = f2bf(acc[nf][r] + bias);
            }
        } else {               // v: c = n - 64
            int c = n - 64;
            bf4 pv;
#pragma unroll
            for (int r = 0; r < 4; ++r) pv[r] = f2bf(acc[nf][r] + bias);
            size_t addr = (size_t)(b * 256 + (i_base >> 4)) * 4096
                        + (size_t)(c >> 5) * 512
                        + (size_t)((c & 31) + 32 * ((i_base >> 3) & 1)) * 8
                        + (i_base & 7);
            *(bf4*)(vf + addr) = pv;
        }
    }
}

// ---------------- K3: Z_i = sum_j exp(q_i . k_j), swapped operands ----------
// S = mfma(A=K rows j, B=Q cols i): i on lanes, j on regs -> j-reduce in-lane.
__global__ __launch_bounds__(256) void zsum_kernel(
    const short* __restrict__ qF, const short* __restrict__ kF,
    float* __restrict__ zpart)
{
    const int l = threadIdx.x & 63, w = threadIdx.x >> 6;
    const int b = blockIdx.y;
    const int itile = blockIdx.x;            // 0..127

    const short* qp = qF + (size_t)(b * 128 + itile) * 1024 + l * 8;
    bf8 qb0 = *(const bf8*)(qp);
    bf8 qb1 = *(const bf8*)(qp + 512);

    float zacc = 0.f;
    const short* kbase = kF + (size_t)b * 131072 + (size_t)w * 32768 + l * 8;
    for (int jt = 0; jt < 32; ++jt) {
        const short* kp = kbase + jt * 1024;
        bf8 kA0 = *(const bf8*)(kp);
        bf8 kA1 = *(const bf8*)(kp + 512);
        f32x16 S = z16();
        S = __builtin_amdgcn_mfma_f32_32x32x16_bf16(kA0, qb0, S, 0, 0, 0);
        S = __builtin_amdgcn_mfma_f32_32x32x16_bf16(kA1, qb1, S, 0, 0, 0);
#pragma unroll
        for (int r = 0; r < 16; ++r) zacc += __expf(fminf(S[r], 80.f));
    }
    zacc += __shfl_xor(zacc, 32);
    if (l < 32)
        zpart[(size_t)w * 16384 + b * 4096 + itile * 32 + l] = zacc;
}

// ---------------- K3b: rz = 1 / sum(partials) --------------------------------
__global__ __launch_bounds__(256) void zfinish(
    const float* __restrict__ zpart, float* __restrict__ rz)
{
    int i = blockIdx.x * 256 + threadIdx.x;   // 0..16383
    float z = zpart[i] + zpart[16384 + i] + zpart[32768 + i] + zpart[49152 + i];
    rz[i] = 1.0f / z;
}

// ---------------- K4: vs = v / Z  (in place on vF) ---------------------------
// vF flat elem a: b = a>>20; it = (a&1048575)>>12; lane = (a>>3)&63;
// i = it*16 + (lane>>5)*8 + (a&7)  -> each bf8 spans 8 consecutive i.
__global__ __launch_bounds__(256) void vscale(
    short* __restrict__ vF, const float* __restrict__ rz)
{
    int t = blockIdx.x * 256 + threadIdx.x;      // 0..524287
    size_t base = (size_t)t * 8;
    int b   = (int)(base >> 20);
    int rem = (int)(base & 1048575);
    int it  = rem >> 12;
    int sub = (rem >> 8) & 1;                    // lane>>5
    int i0  = it * 16 + sub * 8;
    bf8 v = *(bf8*)(vF + base);
    const float* rzp = rz + b * 4096 + i0;
    f32x4 r0 = *(const f32x4*)(rzp);
    f32x4 r1 = *(const f32x4*)(rzp + 4);
#pragma unroll
    for (int e = 0; e < 4; ++e) {
        v[e]     = f2bf(bf2f(v[e])     * r0[e]);
        v[e + 4] = f2bf(bf2f(v[e + 4]) * r1[e]);
    }
    *(bf8*)(vF + base) = v;
}

// ---------------- K5: out = gamma * (P^T @ vs) + x ---------------------------
// Grid 256 = 8 XCD x 32: XCD x -> (b = x>>1, ch = x&1), 32 j-tiles of 128.
// Block 512 = 8 waves = (4 wj) x (2 i-halves). Wave: j32 x c128, 64 i32-steps.
// Softmax in-register (C-frag -> cvt_pk+permlane -> PV A-frags), 1/Z in vs.
// Epilogue: LDS reduce across the 2 i-half waves.
__global__ __launch_bounds__(512) void attn_out(
    const short* __restrict__ qF, const short* __restrict__ kF,
    const short* __restrict__ vF,
    const float* __restrict__ x, const float* __restrict__ gammaPtr,
    float* __restrict__ out)
{
    __shared__ float red[4][32][128];            // 64 KB, epilogue only
    const int l = threadIdx.x & 63, w = threadIdx.x >> 6;
    const int lr = l & 31, hi = l >> 5;
    const int wj = w & 3, isub = w >> 2;

    const int xcd = blockIdx.x & 7, k = blockIdx.x >> 3;
    const int b = xcd >> 1, ch = xcd & 1, jt = k;
    const int j0 = jt * 128;
    const int c0 = ch * 128;

    const short* kfp = kF + (size_t)(b * 128 + jt * 4 + wj) * 1024 + l * 8;
    bf8 kf0 = *(const bf8*)(kfp);
    bf8 kf1 = *(const bf8*)(kfp + 512);

    f32x16 acc[4];
#pragma unroll
    for (int cf = 0; cf < 4; ++cf) acc[cf] = z16();

    const short* qbase = qF + (size_t)b * 131072 + (size_t)isub * 65536 + l * 8;
    const short* vbase = vF + (size_t)b * 1048576 + (size_t)isub * 524288
                       + (size_t)(c0 >> 5) * 512 + l * 8;

    // preload t=0
    bf8 q0 = *(const bf8*)(qbase);
    bf8 q1 = *(const bf8*)(qbase + 512);
    bf8 v0[4], v1[4];
#pragma unroll
    for (int cf = 0; cf < 4; ++cf) {
        v0[cf] = *(const bf8*)(vbase + cf * 512);
        v1[cf] = *(const bf8*)(vbase + 4096 + cf * 512);
    }

    for (int t = 0; t < 64; ++t) {
        bf8 nq0, nq1, nv0[4], nv1[4];
        if (t < 63) {
            const short* qn = qbase + (t + 1) * 1024;
            nq0 = *(const bf8*)(qn);
            nq1 = *(const bf8*)(qn + 512);
            const short* vn = vbase + (size_t)(t + 1) * 8192;
#pragma unroll
            for (int cf = 0; cf < 4; ++cf) {
                nv0[cf] = *(const bf8*)(vn + cf * 512);
                nv1[cf] = *(const bf8*)(vn + 4096 + cf * 512);
            }
        }

        f32x16 S = z16();
        S = __builtin_amdgcn_mfma_f32_32x32x16_bf16(q0, kf0, S, 0, 0, 0);
        S = __builtin_amdgcn_mfma_f32_32x32x16_bf16(q1, kf1, S, 0, 0, 0);

        float p[16];
#pragma unroll
        for (int r = 0; r < 16; ++r) p[r] = __expf(fminf(S[r], 80.f));

        unsigned X0 = cvtpk(p[0],  p[1]),  Y0 = cvtpk(p[4],  p[5]);
        unsigned X1 = cvtpk(p[2],  p[3]),  Y1 = cvtpk(p[6],  p[7]);
        unsigned X2 = cvtpk(p[8],  p[9]),  Y2 = cvtpk(p[12], p[13]);
        unsigned X3 = cvtpk(p[10], p[11]), Y3 = cvtpk(p[14], p[15]);
        asm("v_permlane32_swap_b32 %0, %1" : "+v"(X0), "+v"(Y0));
        asm("v_permlane32_swap_b32 %0, %1" : "+v"(X1), "+v"(Y1));
        asm("v_permlane32_swap_b32 %0, %1" : "+v"(X2), "+v"(Y2));
        asm("v_permlane32_swap_b32 %0, %1" : "+v"(X3), "+v"(Y3));
        u32x4 a0w = {X0, X1, Y0, Y1};
        u32x4 a1w = {X2, X3, Y2, Y3};
        bf8 A0 = __builtin_bit_cast(bf8, a0w);
        bf8 A1 = __builtin_bit_cast(bf8, a1w);

        __builtin_amdgcn_s_setprio(1);
#pragma unroll
        for (int cf = 0; cf < 4; ++cf) {
            acc[cf] = __builtin_amdgcn_mfma_f32_32x32x16_bf16(A0, v0[cf], acc[cf], 0, 0, 0);
            acc[cf] = __builtin_amdgcn_mfma_f32_32x32x16_bf16(A1, v1[cf], acc[cf], 0, 0, 0);
        }
        __builtin_amdgcn_s_setprio(0);

        q0 = nq0; q1 = nq1;
#pragma unroll
        for (int cf = 0; cf < 4; ++cf) { v0[cf] = nv0[cf]; v1[cf] = nv1[cf]; }
    }

    // epilogue: combine the two i-half waves via LDS
    if (isub == 1) {
#pragma unroll
        for (int cf = 0; cf < 4; ++cf)
#pragma unroll
            for (int r = 0; r < 16; ++r) {
                int jrow = (r & 3) + 8 * (r >> 2) + 4 * hi;
                red[wj][jrow][cf * 32 + lr] = acc[cf][r];
            }
    }
    __syncthreads();
    if (isub == 0) {
        const float gamma = *gammaPtr;
#pragma unroll
        for (int cf = 0; cf < 4; ++cf)
#pragma unroll
            for (int r = 0; r < 16; ++r) {
                int jrow = (r & 3) + 8 * (r >> 2) + 4 * hi;
                float s = acc[cf][r] + red[wj][jrow][cf * 32 + lr];
                int j = j0 + wj * 32 + jrow;
                size_t idx = (size_t)(b * 4096 + j) * 256 + c0 + cf * 32 + lr;
                out[idx] = gamma * s + x[idx];
            }
    }
}

extern "C" void kernel_launch(void* const* d_in, const int* in_sizes, int n_in,
                              void* d_out, int out_size, void* d_ws, size_t ws_size,
                              hipStream_t stream)
{
    const float* x  = (const float*)d_in[0];
    const float* Wq = (const float*)d_in[1];
    const float* bq = (const float*)d_in[2];
    const float* Wk = (const float*)d_in[3];
    const float* bk = (const float*)d_in[4];
    const float* Wv = (const float*)d_in[5];
    const float* bv = (const float*)d_in[6];
    const float* gm = (const float*)d_in[7];
    float* out = (float*)d_out;

    char* wsb = (char*)d_ws;
    short* qf    = (short*)(wsb);
    short* kf    = (short*)(wsb + (1u << 20));
    short* vf    = (short*)(wsb + (2u << 20));
    short* wallF = (short*)(wsb + (10u << 20));
    float* ball  = (float*)(wsb + (10u << 20) + 163840);
    float* zpart = (float*)(wsb + (10u << 20) + 163840 + 1280);
    float* rz    = (float*)(wsb + (10u << 20) + 163840 + 1280 + 262144);

    pack_weights<<<320, 256, 0, stream>>>(Wq, Wk, Wv, bq, bk, bv, wallF, ball);
    qkv_gemm<<<256, 256, 0, stream>>>(x, wallF, ball, qf, kf, vf);
    zsum_kernel<<<dim3(128, 4), 256, 0, stream>>>(qf, kf, zpart);
    zfinish<<<64, 256, 0, stream>>>(zpart, rz);
    vscale<<<2048, 256, 0, stream>>>(vf, rz);
    attn_out<<<256, 512, 0, stream>>>(qf, kf, vf, x, gm, out);
}